// Round 10
// baseline (308.187 us; speedup 1.0000x reference)
//
#include <hip/hip_runtime.h>
#include <cstdint>
#include <cmath>

// ---------------------------------------------------------------------------
// LlamaAttention round 17 (= R16 resubmit; R16 bench was an infra failure,
// "MI355X container failed twice" — no kernel result. Audit found no OOB /
// barrier / lds-uniformity defect; theory unchanged).
// R16: flash staging via global_load_lds (m97 pattern).
//   B=2 L=2048 D=2048 H=16 KV=4 DH=128, causal + key-padding mask, RoPE.
// R15 POST-MORTEM: total 298.4 (-8.7). QKV flat at 85 despite trig halved +
//   occupancy restored => RoPE tail not trig-bound; table idea dropped.
// R16 (flash only): replace register staging (4 loads + 6 ds_writes + addr
//   VALU/thread/round) with global_load_lds width=16 (common-mistake #1):
//   - LDS dest LINEAR (tid*16 + p*8192) per m104; per-lane GLOBAL source
//     pre-swizzled (rule #21/m173): K chunk = kch ^ (krow&7) — LDS content
//     identical to old XOR layout, K read side unchanged.
//   - V: natural key order + row-XOR (old 8B interleave not DMA-able);
//     PV reads A-frags via 4x ds_read_b64 at (kt*32+quad*8)^rsw.
//   - Round r: gld_lds tile r+1 -> buf[cur^1] at TOP (async, lands under
//     compute); ONE __syncthreads per round drains vmcnt. kl/vl deleted.
// Kept: 512x512 blocks, pair {c,31-c}, dbuf, reg-P via K=16 PV MFMA, exp2
//   softmax, per-lane defer-max, lane-partial l_i, setprio, amask->Bb.
// MFMA layouts (learn_hip m89/m91): A[m=l15][k], B[k][n=l15],
//   C/D: col=l15, row=quad*4+reg (shape-determined).
// ---------------------------------------------------------------------------

typedef __bf16 bf16_t;
typedef __bf16 bf16x8 __attribute__((ext_vector_type(8)));
typedef __bf16 bf16x4 __attribute__((ext_vector_type(4)));
typedef float  f32x4  __attribute__((ext_vector_type(4)));

#define HQ   16
#define HKV  4
#define GQA  4
#define DHD  128
#define BB   2
#define LL   2048
#define DDIM 2048
#define MINV (-1e15f)
// 1/sqrt(128) * log2(e): folded into Q at epilogue time so flash uses exp2.
#define QSC  0.12751744f

static __device__ __forceinline__ f32x4 mfma16(bf16x8 a, bf16x8 b, f32x4 c) {
  return __builtin_amdgcn_mfma_f32_16x16x32_bf16(a, b, c, 0, 0, 0);
}

// K=16 bf16 MFMA (PV step): A/B are 4 bf16 per lane, k = quad*4+j.
static __device__ __forceinline__ f32x4 mfma16k16(bf16x4 a, bf16x4 b, f32x4 c) {
#if __has_builtin(__builtin_amdgcn_mfma_f32_16x16x16bf16_1k)
  typedef short s4 __attribute__((ext_vector_type(4)));
  union U { bf16x4 h; s4 s; };
  U ua, ub; ua.h = a; ub.h = b;
  return __builtin_amdgcn_mfma_f32_16x16x16bf16_1k(ua.s, ub.s, c, 0, 0, 0);
#elif __has_builtin(__builtin_amdgcn_mfma_f32_16x16x16_bf16)
  return __builtin_amdgcn_mfma_f32_16x16x16_bf16(a, b, c, 0, 0, 0);
#else
  f32x4 d;
  asm volatile("v_mfma_f32_16x16x16_bf16 %0, %1, %2, %3"
               : "=v"(d) : "v"(a), "v"(b), "v"(c));
  return d;
#endif
}

#if __has_builtin(__builtin_amdgcn_exp2f)
#define EXP2F(x) __builtin_amdgcn_exp2f(x)
#else
#define EXP2F(x) exp2f(x)
#endif

static __device__ __forceinline__ void gld16(const bf16_t* g, bf16_t* l) {
  __builtin_amdgcn_global_load_lds(
      (const __attribute__((address_space(1))) void*)g,
      (__attribute__((address_space(3))) void*)l,
      16, 0, 0);
}

// ---------------- f32 -> bf16 cast (5 tensors in one launch) ----------------
struct CastArgs {
  const float* s[5];
  bf16_t* d[5];
  int n[5];
};

__global__ __launch_bounds__(256) void cast5_kernel(CastArgs a) {
  const int t = blockIdx.y;
  const int i8 = (blockIdx.x * 256 + threadIdx.x) * 8;
  if (i8 >= a.n[t]) return;
  const float4* s = (const float4*)(a.s[t] + i8);
  float4 x = s[0], y = s[1];
  bf16x8 o = {(bf16_t)x.x, (bf16_t)x.y, (bf16_t)x.z, (bf16_t)x.w,
              (bf16_t)y.x, (bf16_t)y.y, (bf16_t)y.z, (bf16_t)y.w};
  *(bf16x8*)(a.d[t] + i8) = o;
}

// ---------------------------------------------------------------------------
// Tiled GEMM: C = A(MxK) * W(NxK)^T, 128x128 tile, BK=32 (m97 structure).
// Wave n-columns: colof(ni) = (ni&1)*16 + (ni>>1)*64 + (wave&1)*32 -- a pure
// permutation of the 8 16-col blocks so each wave owns {dl, dl+64} pairs.
// STORE 2: f32 row-major -> C0 (permuted store indices).
// STORE 3: fused QKV epilogue (N=3072) WITH THREAD-LOCAL RoPE:
//   cols [0,2048): q -> C0 bf16 row-major, RoPE'd + QSC-scaled.
//   cols [2048,2560): k -> Ck bf16 row-major (N=512), RoPE'd.
//   cols [2560,3072): v -> Cv transposed (B,KV,DH,L), bf16x4 along L.
//   RoPE: partner of acc[mi][ni] (dl) is acc[mi][ni^2] (dl+64), same lane;
//   one __sincosf per (dl,l) serves both halves. No LDS, no barriers.
// ---------------------------------------------------------------------------
template <int STORE>
__global__ __launch_bounds__(256) void gemm_tile(const bf16_t* __restrict__ A,
                                                 const bf16_t* __restrict__ W,
                                                 void* __restrict__ C0,
                                                 bf16_t* __restrict__ Ck,
                                                 bf16_t* __restrict__ Cv,
                                                 int M, int N, int K) {
  __shared__ __align__(16) bf16_t As[128 * 32];
  __shared__ __align__(16) bf16_t Bs[128 * 32];
  const int tid  = threadIdx.x;
  const int lane = tid & 63;
  const int wave = tid >> 6;
  const int l15  = lane & 15;
  const int quad = lane >> 4;
  const int m0 = blockIdx.y * 128;
  const int n0 = blockIdx.x * 128;

  const int srow = wave * 32 + (lane >> 2);
  const int scol = (lane & 3) * 8;
  const bf16_t* ag = A + (size_t)(m0 + srow) * K + scol;
  const bf16_t* wg = W + (size_t)(n0 + srow) * K + scol;
  bf16_t* al = As + wave * 1024;
  bf16_t* bl = Bs + wave * 1024;

  const int wm   = (wave >> 1) * 64;
  const int nsel = wave & 1;
  // colof(ni): n-offset of frag ni within the 128-col tile.
  auto colof = [&](int ni) { return ((ni & 1) << 4) + ((ni >> 1) << 6) + (nsel << 5); };

  f32x4 acc[4][4];
#pragma unroll
  for (int mi = 0; mi < 4; mi++)
#pragma unroll
    for (int ni = 0; ni < 4; ni++) acc[mi][ni] = {0.f, 0.f, 0.f, 0.f};

  for (int k0 = 0; k0 < K; k0 += 32) {
    __syncthreads();
    gld16(ag + k0, al);
    gld16(ag + k0 + (size_t)16 * K, al + 512);
    gld16(wg + k0, bl);
    gld16(wg + k0 + (size_t)16 * K, bl + 512);
    __syncthreads();
    bf16x8 af[4], bfr[4];
#pragma unroll
    for (int mi = 0; mi < 4; mi++)
      af[mi] = *(const bf16x8*)(As + (wm + mi * 16 + l15) * 32 + quad * 8);
#pragma unroll
    for (int ni = 0; ni < 4; ni++)
      bfr[ni] = *(const bf16x8*)(Bs + (colof(ni) + l15) * 32 + quad * 8);
#pragma unroll
    for (int mi = 0; mi < 4; mi++)
#pragma unroll
      for (int ni = 0; ni < 4; ni++)
        acc[mi][ni] = mfma16(af[mi], bfr[ni], acc[mi][ni]);
  }

  if (STORE == 2) {
    float* C = (float*)C0;
#pragma unroll
    for (int mi = 0; mi < 4; mi++) {
      const int row = m0 + wm + mi * 16 + quad * 4;
#pragma unroll
      for (int ni = 0; ni < 4; ni++) {
        const int col = n0 + colof(ni) + l15;
#pragma unroll
        for (int i = 0; i < 4; i++)
          C[(size_t)(row + i) * N + col] = acc[mi][ni][i];
      }
    }
  } else {  // STORE == 3
    if (n0 < 2560) {
      // q or k tile: thread-local RoPE. dl = low half dim of this lane's pair.
      const bool isq = (n0 < 2048);
#pragma unroll
      for (int mi = 0; mi < 4; mi++) {
        const int row = m0 + wm + mi * 16 + quad * 4;
#pragma unroll
        for (int ni2 = 0; ni2 < 2; ni2++) {
          const int dl = (nsel << 5) + (ni2 << 4) + l15;   // 0..63
          // invf = 10000^(-dl/64)  (identical math to old rope_kernel)
          const float invf = __expf(-(float)dl * 0.14391156862532788f);
#pragma unroll
          for (int i = 0; i < 4; i++) {
            const int l = (row + i) & (LL - 1);
            float sn, cs;
            __sincosf((float)l * invf, &sn, &cs);
            const float x1 = acc[mi][ni2][i];        // d = dl
            const float x2 = acc[mi][ni2 | 2][i];    // d = dl + 64
            const float out_lo = x1 * cs - x2 * sn;
            const float out_hi = x2 * cs + x1 * sn;
            if (isq) {
              bf16_t* base = (bf16_t*)C0 + (size_t)(row + i) * 2048 + n0;
              base[dl]      = (bf16_t)(out_lo * QSC);
              base[dl + 64] = (bf16_t)(out_hi * QSC);
            } else {
              bf16_t* base = Ck + (size_t)(row + i) * 512 + (n0 - 2048);
              base[dl]      = (bf16_t)out_lo;
              base[dl + 64] = (bf16_t)out_hi;
            }
          }
        }
      }
    } else {
      // v tile: transposed store, no RoPE (permuted col indices).
#pragma unroll
      for (int mi = 0; mi < 4; mi++) {
        const int row = m0 + wm + mi * 16 + quad * 4;
        const int b = row >> 11;
        const int l0 = row & (LL - 1);
#pragma unroll
        for (int ni = 0; ni < 4; ni++) {
          const int kvcol = n0 - 2560 + colof(ni) + l15;
          const int kvh = kvcol >> 7, d = kvcol & 127;
          bf16x4 w4 = {(bf16_t)acc[mi][ni][0], (bf16_t)acc[mi][ni][1],
                       (bf16_t)acc[mi][ni][2], (bf16_t)acc[mi][ni][3]};
          *(bf16x4*)(Cv + ((size_t)(b * HKV + kvh) * DHD + d) * LL + l0) = w4;
        }
      }
    }
  }
}

// ---------------------------------------------------------------------------
// Flash attention: 512 blocks x 512 threads (8 waves). Block owns 128-row
// tile pair {c, 31-c}: waves 0-3 -> tile c (16-row strips), waves 4-7 ->
// tile 31-c. KV round = 64 keys, double-buffered LDS, 1 barrier/round.
// STAGING: global_load_lds width=16, LINEAR LDS dest (tid*16+p*8192),
//   per-lane pre-swizzled global source chunk (^ row&7) per rule #21/m173.
// Kbuf[key 0..63][d 0..127]: LDS[r][chunk j] = global[r][chunk j^(r&7)];
//   K reads (b128 at ^rsw) unchanged from R15.
// Vbuf[d 0..127][key 0..63]: same row-XOR, NATURAL key order; PV A-frags
//   via 4x ds_read_b64 at (kt*32 + quad*8) ^ rsw (granule XOR within row).
// Round r: gld_lds tile r+1 -> buf[cur^1] at top (async, lands under
//   compute); compute from buf[cur]; __syncthreads (drains vmcnt); swap.
// Softmax: exp2 domain, per-lane defer-max, lane-partial l_i; setprio MFMA.
// ---------------------------------------------------------------------------
__global__ __launch_bounds__(512, 4) void flash_attn2(const bf16_t* __restrict__ q,
                                                      const bf16_t* __restrict__ k,
                                                      const bf16_t* __restrict__ vt,
                                                      const int* __restrict__ amask,
                                                      bf16_t* __restrict__ o) {
  __shared__ __align__(16) bf16_t Kbuf[2][64 * 128];   // 2 x 16 KB swizzled
  __shared__ __align__(16) bf16_t Vbuf[2][128 * 64];   // 2 x 16 KB swizzled
  __shared__ __align__(16) float  Bb[2048];            // 8 KB bias row

  const int tid  = threadIdx.x;
  const int lane = tid & 63;
  const int wave = tid >> 6;
  const int l15  = lane & 15;
  const int quad = lane >> 4;

  // 512 blocks, 2/CU: co-resident pair {i, i+256} -> c and 15-c
  // (rounds (32-c) + (17+c) = 49, balanced per CU).
  const int bi   = blockIdx.x;
  const int half = bi >> 8;
  const int jj   = bi & 255;
  const int cc   = jj >> 5;
  const int c    = half ? (15 - cc) : cc;          // 0..15
  const int bh = jj & 31;
  const int b  = bh >> 4;
  const int h  = bh & 15;
  const int kv = h >> 2;

  const int tile = (wave < 4) ? c : (31 - c);      // 64-row tile index
  const int q0   = tile * 64 + (wave & 3) * 16;    // this wave's 16-row strip
  const int nrounds = 32 - c;                      // 17..32

  bf16x8 qf[4];
  {
    const bf16_t* qb = q + ((size_t)(b * LL + q0 + l15)) * (HQ * DHD) + h * DHD + quad * 8;
#pragma unroll
    for (int t = 0; t < 4; t++) qf[t] = *(const bf16x8*)(qb + 32 * t);
  }

  f32x4 acc[8];
#pragma unroll
  for (int mt = 0; mt < 8; mt++) acc[mt] = {0.f, 0.f, 0.f, 0.f};
  float m_i = -1e30f;      // per-row (uniform across the row's 4 quads)
  float l_i = 0.f;         // LANE-PARTIAL (this quad's keys); reduced at end

  const bf16_t* kg_base = k + ((size_t)(b * LL)) * (HKV * DHD) + kv * DHD;
  const bf16_t* vg_base = vt + ((size_t)(b * HKV + kv) * DHD) * LL;

  // Bias row from amask -> LDS (once; 512 threads x int4 = 2048 entries).
  {
    int4 am = ((const int4*)(amask + b * LL))[tid];
    f32x4 bv = { am.x ? 0.f : MINV, am.y ? 0.f : MINV,
                 am.z ? 0.f : MINV, am.w ? 0.f : MINV };
    ((f32x4*)Bb)[tid] = bv;
  }

  // Staging geometry: K tile 64x256B = 512 thr x 2 chunks of 16B (rows
  // krow + p*32); V tile 128x128B = 512 thr x 2 chunks (rows vrow + p*64).
  // LDS dest is LINEAR: byte tid*16 + p*8192 (wave-uniform base + lane*16).
  // Global source chunk pre-XOR'd by (row&7)  ->  same content as old swz.
  const int krow = tid >> 4, kch = tid & 15;       // krow 0..31
  const int vrow = tid >> 3, vch = tid & 7;        // vrow 0..63
  const int rsw  = (l15 & 7) << 4;                 // read-side swizzle

  const bf16_t* ksrc = kg_base + (size_t)krow * (HKV * DHD) + (kch ^ (krow & 7)) * 8;
  const bf16_t* vsrc = vg_base + (size_t)vrow * LL + (vch ^ (vrow & 7)) * 8;
  const int ldst = wave * 512;   // wave-uniform LDS base (elements)

  auto STAGE_ASYNC = [&](int j0, int bsel) {
    bf16_t* kb = &Kbuf[bsel][0] + ldst;
    bf16_t* vb = &Vbuf[bsel][0] + ldst;
#pragma unroll
    for (int p = 0; p < 2; p++)
      gld16(ksrc + (size_t)(j0 + p * 32) * (HKV * DHD), kb + p * 4096);
#pragma unroll
    for (int p = 0; p < 2; p++)
      gld16(vsrc + j0 + (size_t)(p * 64) * LL, vb + p * 4096);
  };

  // Prologue: tile 0 -> buf0 (async) + drain.
  STAGE_ASYNC(0, 0);
  __syncthreads();

  int cur = 0;
  for (int r = 0; r < nrounds; r++) {
    const int j0 = r * 64;
    const bool last = (r + 1 >= nrounds);
    if (!last) STAGE_ASYNC(j0 + 64, cur ^ 1);   // async; lands under compute

    const bool act = (j0 <= q0 + 15);   // wave-uniform
    if (act) {
      const char* KbC = (const char*)(&Kbuf[cur][0]);
      const char* VbC = (const char*)(&Vbuf[cur][0]);

      // ---- QK^T (S^T): A = K row, B = Q^T; D row = key (quad*4+i), col = qrow.
      f32x4 s[4];
      __builtin_amdgcn_s_setprio(1);
#pragma unroll
      for (int kt = 0; kt < 4; kt++) {
        const char* kr = KbC + (size_t)(kt * 16 + l15) * 256;
        f32x4 s0 = {0.f, 0.f, 0.f, 0.f};
#pragma unroll
        for (int t = 0; t < 4; t++) {
          bf16x8 kf = *(const bf16x8*)(kr + ((quad * 16 + t * 64) ^ rsw));
          s0 = mfma16(kf, qf[t], s0);
        }
        s[kt] = s0;
      }
      __builtin_amdgcn_s_setprio(0);

      // ---- online softmax in log2 domain (Q pre-scaled by QSC). P stays in
      //      registers: lane's p4 per kt IS the K=16 B-frag for PV.
      const int qrow = q0 + l15;
      const bool diag = (j0 + 63 > q0);      // mask iff max key > min row
      float mx = -1e30f;                     // per-lane partial max
#pragma unroll
      for (int kt = 0; kt < 4; kt++) {
        f32x4 sv = s[kt];
        f32x4 bv = *(const f32x4*)(&Bb[j0 + kt * 16 + quad * 4]);
#pragma unroll
        for (int i = 0; i < 4; i++) {
          float x = sv[i] + bv[i];
          if (diag) {
            int key = j0 + kt * 16 + quad * 4 + i;
            if (key > qrow) x = MINV;
          }
          sv[i] = x;
          mx = fmaxf(mx, x);
        }
        s[kt] = sv;
      }
      // defer-max (T13) with PER-LANE partial max: __all() reduces across the
      // wave, so this is equivalent to checking the row-reduced max. The two
      // max-shuffles only run on the rare rescale path.
      if (!__all(mx <= m_i + 8.0f)) {
        mx = fmaxf(mx, __shfl_xor(mx, 16));
        mx = fmaxf(mx, __shfl_xor(mx, 32));   // now per-row max
        const float mn = fmaxf(m_i, mx);
        const float alpha = EXP2F(m_i - mn);
        m_i = mn;
        l_i *= alpha;
#pragma unroll
        for (int mt = 0; mt < 8; mt++) {
          acc[mt][0] *= alpha; acc[mt][1] *= alpha;
          acc[mt][2] *= alpha; acc[mt][3] *= alpha;
        }
      }
      const float mn = m_i;
      float sum = 0.f;
      bf16x4 pf[4];
#pragma unroll
      for (int kt = 0; kt < 4; kt++) {
        f32x4 sv = s[kt];
        bf16x4 p4;
#pragma unroll
        for (int i = 0; i < 4; i++) {
          float pe = EXP2F(sv[i] - mn);
          sum += pe;
          p4[i] = (bf16_t)pe;
        }
        pf[kt] = p4;
      }
      l_i += sum;    // lane-partial; cross-quad reduce deferred to epilogue

      // ---- PV with K=16 MFMA: A = V^T frag read from natural-order rows
      //      (4x ds_read_b64, granule-XOR rsw); B = pf (lane-local).
      //      acc layout: row=d (mt*16+quad*4+i), col=qrow.
      __builtin_amdgcn_s_setprio(1);
#pragma unroll
      for (int mt = 0; mt < 8; mt++) {
        const char* vr = VbC + (size_t)(mt * 16 + l15) * 128;
        bf16x4 va = *(const bf16x4*)(vr + ((quad * 8) ^ rsw));
        bf16x4 vb = *(const bf16x4*)(vr + ((32 + quad * 8) ^ rsw));
        bf16x4 vc = *(const bf16x4*)(vr + ((64 + quad * 8) ^ rsw));
        bf16x4 vd = *(const bf16x4*)(vr + ((96 + quad * 8) ^ rsw));
        acc[mt] = mfma16k16(va, pf[0], acc[mt]);
        acc[mt] = mfma16k16(vb, pf[1], acc[mt]);
        acc[mt] = mfma16k16(vc, pf[2], acc[mt]);
        acc[mt] = mfma16k16(vd, pf[3], acc[mt]);
      }
      __builtin_amdgcn_s_setprio(0);
    }

    // ---- single barrier per round: drains this round's gld_lds (vmcnt)
    //      and closes reads of buf[cur]; then swap.
    if (!last) {
      __syncthreads();
      cur ^= 1;
    }
  }

  {
    // Epilogue: reduce the lane-partial l_i across the row's 4 quads (once).
    l_i += __shfl_xor(l_i, 16);
    l_i += __shfl_xor(l_i, 32);
    const float invl = 1.0f / l_i;
    bf16_t* ob = o + ((size_t)(b * LL + q0 + l15)) * (HQ * DHD) + h * DHD + quad * 4;
#pragma unroll
    for (int mt = 0; mt < 8; mt++) {
      f32x4 a = acc[mt];
      bf16x4 w = {(bf16_t)(a[0] * invl), (bf16_t)(a[1] * invl),
                  (bf16_t)(a[2] * invl), (bf16_t)(a[3] * invl)};
      *(bf16x4*)(ob + mt * 16) = w;
    }
  }
}

extern "C" void kernel_launch(void* const* d_in, const int* in_sizes, int n_in,
                              void* d_out, int out_size, void* d_ws, size_t ws_size,
                              hipStream_t stream) {
  const float* hidden = (const float*)d_in[0];
  const int*   amask  = (const int*)d_in[1];
  const float* Wq     = (const float*)d_in[2];
  const float* Wk     = (const float*)d_in[3];
  const float* Wv     = (const float*)d_in[4];
  const float* Wo     = (const float*)d_in[5];
  float* out = (float*)d_out;

  const int M = BB * LL;           // 4096
  const size_t MB = 1u << 20;
  char* ws = (char*)d_ws;
  bf16_t* hid_b   = (bf16_t*)(ws);            // 16 MB  (B,L,D)
  bf16_t* q_ws    = (bf16_t*)(ws + 16 * MB);  // 16 MB
  bf16_t* attn_ws = (bf16_t*)(ws + 32 * MB);  // 16 MB
  bf16_t* k_ws    = (bf16_t*)(ws + 48 * MB);  //  4 MB
  bf16_t* vt_ws   = (bf16_t*)(ws + 52 * MB);  //  4 MB
  bf16_t* wqkv_b  = (bf16_t*)(ws + 56 * MB);  // 12 MB: Wq(8) + Wk(2) + Wv(2)
  bf16_t* wq_b    = wqkv_b;
  bf16_t* wk_b    = (bf16_t*)(ws + 64 * MB);
  bf16_t* wv_b    = (bf16_t*)(ws + 66 * MB);
  bf16_t* wo_b    = (bf16_t*)(ws + 68 * MB);  //  8 MB

  CastArgs ca;
  ca.s[0] = hidden; ca.d[0] = hid_b; ca.n[0] = BB * LL * DDIM;
  ca.s[1] = Wq;     ca.d[1] = wq_b;  ca.n[1] = HQ * DHD * DDIM;
  ca.s[2] = Wk;     ca.d[2] = wk_b;  ca.n[2] = HKV * DHD * DDIM;
  ca.s[3] = Wv;     ca.d[3] = wv_b;  ca.n[3] = HKV * DHD * DDIM;
  ca.s[4] = Wo;     ca.d[4] = wo_b;  ca.n[4] = DDIM * DDIM;
  {
    int maxn = BB * LL * DDIM;
    dim3 g((maxn / 8 + 255) / 256, 5);
    cast5_kernel<<<g, 256, 0, stream>>>(ca);
  }

  gemm_tile<3><<<dim3(3072 / 128, M / 128), 256, 0, stream>>>(
      hid_b, wqkv_b, q_ws, k_ws, vt_ws, M, 3072, DDIM);

  flash_attn2<<<512, 512, 0, stream>>>(q_ws, k_ws, vt_ws, amask, attn_ws);

  gemm_tile<2><<<dim3(DDIM / 128, M / 128), 256, 0, stream>>>(
      attn_ws, wo_b, (void*)out, nullptr, nullptr, M, DDIM, DDIM);
}